// Round 1
// baseline (604.165 us; speedup 1.0000x reference)
//
#include <hip/hip_runtime.h>
#include <math.h>

#define NROWS (64 * 4096)        // 262144 rows
#define D     64
#define K     1024
#define NELEM ((size_t)NROWS * (size_t)D)   // 16777216

// ws layout (bytes):
// [0,     4096)  float norms[1024]
// [4096,  8192)  uint  counts[1024]        (must be zeroed each call)
// [8192, 12288)  float block_loss[1024]    (every block writes -> no zeroing needed)

#define DOT4(acc, a, e) \
  acc = fmaf((a).x, (e).x, fmaf((a).y, (e).y, fmaf((a).z, (e).z, fmaf((a).w, (e).w, (acc)))))

#define SQD4(acc, a, e) { \
  float _dx = (e).x - (a).x, _dy = (e).y - (a).y, _dz = (e).z - (a).z, _dw = (e).w - (a).w; \
  acc = fmaf(_dx, _dx, fmaf(_dy, _dy, fmaf(_dz, _dz, fmaf(_dw, _dw, (acc))))); }

__global__ __launch_bounds__(256) void vq_norms(const float* __restrict__ cb,
                                                float* __restrict__ norms) {
  int k = blockIdx.x * blockDim.x + threadIdx.x;
  if (k >= K) return;
  const float4* e4 = (const float4*)(cb + (k << 6));
  float a0 = 0.f, a1 = 0.f, a2 = 0.f, a3 = 0.f;
#pragma unroll
  for (int j = 0; j < 16; j += 4) {
    float4 e;
    e = e4[j + 0]; DOT4(a0, e, e);
    e = e4[j + 1]; DOT4(a1, e, e);
    e = e4[j + 2]; DOT4(a2, e, e);
    e = e4[j + 3]; DOT4(a3, e, e);
  }
  norms[k] = (a0 + a1) + (a2 + a3);
}

__global__ __launch_bounds__(256) void vq_main(const float* __restrict__ z,
                                               const float* __restrict__ cb,
                                               const float* __restrict__ norms,
                                               float* __restrict__ zq,
                                               unsigned int* __restrict__ counts,
                                               float* __restrict__ block_loss) {
  const int tid = threadIdx.x;
  const int row = blockIdx.x * 256 + tid;

  // z row into registers (64 VGPRs)
  const float4* zr4 = (const float4*)(z + (size_t)row * D);
  float4 zr[16];
#pragma unroll
  for (int j = 0; j < 16; ++j) zr[j] = zr4[j];

  // argmin over k of  m_k = ||e_k||^2 - 2 z.e_k   (||z||^2 is row-constant)
  float best = 3.4e38f;
  int   bidx = 0;
  for (int k = 0; k < K; k += 2) {
    const float4* e0 = (const float4*)(cb + (k << 6));
    const float4* e1 = e0 + 16;
    float a0 = 0.f, a1 = 0.f, a2 = 0.f, a3 = 0.f;
    float b0 = 0.f, b1 = 0.f, b2 = 0.f, b3 = 0.f;
#pragma unroll
    for (int j = 0; j < 16; j += 4) {
      float4 t;
      t = e0[j + 0]; DOT4(a0, zr[j + 0], t);
      t = e1[j + 0]; DOT4(b0, zr[j + 0], t);
      t = e0[j + 1]; DOT4(a1, zr[j + 1], t);
      t = e1[j + 1]; DOT4(b1, zr[j + 1], t);
      t = e0[j + 2]; DOT4(a2, zr[j + 2], t);
      t = e1[j + 2]; DOT4(b2, zr[j + 2], t);
      t = e0[j + 3]; DOT4(a3, zr[j + 3], t);
      t = e1[j + 3]; DOT4(b3, zr[j + 3], t);
    }
    float d0 = (a0 + a1) + (a2 + a3);
    float d1 = (b0 + b1) + (b2 + b3);
    float m0 = fmaf(-2.f, d0, norms[k]);
    float m1 = fmaf(-2.f, d1, norms[k + 1]);
    if (m0 < best) { best = m0; bidx = k; }        // strict < keeps first index (np.argmin)
    if (m1 < best) { best = m1; bidx = k + 1; }
  }

  // epilogue: gather winning code, write z_q, exact row loss
  const float4* eb4 = (const float4*)(cb + (bidx << 6));
  float4* o4 = (float4*)(zq + (size_t)row * D);
  float l0 = 0.f, l1 = 0.f, l2 = 0.f, l3 = 0.f;
#pragma unroll
  for (int j = 0; j < 16; j += 4) {
    float4 e;
    e = eb4[j + 0]; o4[j + 0] = e; SQD4(l0, zr[j + 0], e);
    e = eb4[j + 1]; o4[j + 1] = e; SQD4(l1, zr[j + 1], e);
    e = eb4[j + 2]; o4[j + 2] = e; SQD4(l2, zr[j + 2], e);
    e = eb4[j + 3]; o4[j + 3] = e; SQD4(l3, zr[j + 3], e);
  }
  float row_loss = (l0 + l1) + (l2 + l3);

  atomicAdd(&counts[bidx], 1u);   // integer atomics: deterministic

  // deterministic block reduction of row_loss
  __shared__ float red[256];
  red[tid] = row_loss;
  __syncthreads();
#pragma unroll
  for (int s = 128; s > 0; s >>= 1) {
    if (tid < s) red[tid] += red[tid + s];
    __syncthreads();
  }
  if (tid == 0) block_loss[blockIdx.x] = red[0];
}

__global__ __launch_bounds__(1024) void vq_finalize(const unsigned int* __restrict__ counts,
                                                    const float* __restrict__ block_loss,
                                                    float* __restrict__ out) {
  __shared__ float sh[1024];
  __shared__ float sl[1024];
  const int t = threadIdx.x;
  float c = (float)counts[t];
  float p = c * (1.0f / (float)NROWS);
  sh[t] = p * logf(p + 1e-10f);
  sl[t] = block_loss[t];
  __syncthreads();
#pragma unroll
  for (int s = 512; s > 0; s >>= 1) {
    if (t < s) { sh[t] += sh[t + s]; sl[t] += sl[t + s]; }
    __syncthreads();
  }
  if (t == 0) {
    out[NELEM]     = 1.25f * sl[0] / (float)NELEM;  // q_loss + 0.25*e_loss, both == mean sq diff
    out[NELEM + 1] = expf(-sh[0]);                  // perplexity
  }
}

extern "C" void kernel_launch(void* const* d_in, const int* in_sizes, int n_in,
                              void* d_out, int out_size, void* d_ws, size_t ws_size,
                              hipStream_t stream) {
  const float* z  = (const float*)d_in[0];   // [262144, 64]
  const float* cb = (const float*)d_in[1];   // [1024, 64]
  float* out = (float*)d_out;                // [16777216 z_q | loss | perplexity]

  float*        norms      = (float*)d_ws;
  unsigned int* counts     = (unsigned int*)((char*)d_ws + 4096);
  float*        block_loss = (float*)((char*)d_ws + 8192);

  hipMemsetAsync((char*)d_ws + 4096, 0, 4096, stream);   // zero counts
  vq_norms<<<dim3(4), dim3(256), 0, stream>>>(cb, norms);
  vq_main<<<dim3(NROWS / 256), dim3(256), 0, stream>>>(z, cb, norms, out, counts, block_loss);
  vq_finalize<<<dim3(1), dim3(1024), 0, stream>>>(counts, block_loss, out);
}